// Round 11
// baseline (122.382 us; speedup 1.0000x reference)
//
#include <hip/hip_runtime.h>

// Problem constants
#define B_    8
#define H_    512
#define W_    512
#define KK_   9
#define COUT_ 3
#define HO_   510
#define WO_   510
#define PLANE_ 260100           // HO_*WO_

typedef float f2 __attribute__((ext_vector_type(2)));

__device__ __forceinline__ int iclamp(int v, int lo, int hi) {
    return v < lo ? lo : (v > hi ? hi : v);
}

// ---------- pre-pass: pack 2x2 bilinear quads ----------
// T[b][y][x] = { x[y][x], x[y][x+1], x[y+1][x], x[y+1][x+1] }   (clamped at edges)
__global__ __launch_bounds__(256) void pack_quads(
    const float* __restrict__ x, float4* __restrict__ T)
{
    const int i  = blockIdx.x * 256 + threadIdx.x;   // 8*512*512 threads
    const int xi = i & 511;
    const int y  = (i >> 9) & 511;
    const int b  = i >> 18;
    const float* xb = x + (b << 18);
    const int y1 = y  < 511 ? y  + 1 : 511;
    const int x1 = xi < 511 ? xi + 1 : 511;
    float4 q;
    q.x = xb[(y  << 9) + xi];
    q.y = xb[(y  << 9) + x1];
    q.z = xb[(y1 << 9) + xi];
    q.w = xb[(y1 << 9) + x1];
    T[i] = q;
}

// ---------- main kernel: one float4 gather per bilinear sample ----------
__global__ __launch_bounds__(256) void dcn_fwd_quad(
    const float*  __restrict__ x,       // [B,1,512,512] (slow path only)
    const float4* __restrict__ T,       // [B,512,512] packed quads
    const float*  __restrict__ offset,  // [B,18,510,510]
    const float*  __restrict__ mask,    // [B,9,510,510]
    const float*  __restrict__ weight,  // [3,1,3,3]
    const float*  __restrict__ bias,    // [3]
    float* __restrict__ out)            // [B,3,510,510]
{
    const int bid = blockIdx.x;        // one output row per block
    const int ho  = bid % HO_;
    const int b   = bid / HO_;

    const int j   = threadIdx.x;       // 2 px each
    int wo0 = 2 * j;
    if (wo0 > WO_ - 2) wo0 = WO_ - 2;  // j=255 duplicates last pair (benign)

    const int pix = ho * WO_ + wo0;
    const float*  xb = x + (b << 18);
    const float4* Tb = T + (b << 18);
    const float* offb = offset + b * (2 * KK_ * PLANE_) + pix;
    const float* mb   = mask   + b * (KK_ * PLANE_)    + pix;

    float w0[KK_], w1[KK_], w2[KK_];
    #pragma unroll
    for (int k = 0; k < KK_; ++k) {
        w0[k] = weight[0 * KK_ + k];
        w1[k] = weight[1 * KK_ + k];
        w2[k] = weight[2 * KK_ + k];
    }
    const float b0 = bias[0], b1 = bias[1], b2 = bias[2];

    const float fho = (float)ho;
    const float fwo = (float)wo0;

    float a00 = 0.f, a01 = 0.f;
    float a10 = 0.f, a11 = 0.f;
    float a20 = 0.f, a21 = 0.f;

    #pragma unroll
    for (int kh = 0; kh < 3; ++kh) {
        #pragma unroll
        for (int kw = 0; kw < 3; ++kw) {
            const int kk = kh * 3 + kw;
            const f2 dy2 = *(const f2*)(offb + (2 * kk)     * PLANE_);
            const f2 dx2 = *(const f2*)(offb + (2 * kk + 1) * PLANE_);
            const f2 m2  = *(const f2*)(mb   +  kk          * PLANE_);

            #pragma unroll
            for (int p = 0; p < 2; ++p) {
                const float py = (fho + (float)kh) + dy2[p];
                const float px = (fwo + (float)(kw + p)) + dx2[p];

                const float y0f = floorf(py);
                const float x0f = floorf(px);
                const float ly  = py - y0f;
                const float lx  = px - x0f;

                const int iy0 = (int)y0f;
                const int ix0 = (int)x0f;

                float v00, v01, v10, v11;
                if (__builtin_expect(((unsigned)iy0 < 511u) & ((unsigned)ix0 < 511u), 1)) {
                    // whole 2x2 quad inside image: validity == 1, ONE gather
                    const float4 q = Tb[(iy0 << 9) + ix0];
                    v00 = q.x; v01 = q.y; v10 = q.z; v11 = q.w;
                } else {
                    // border/outside: full reference semantics (rare)
                    const float y1f = y0f + 1.0f, x1f = x0f + 1.0f;
                    const float vy0 = (y0f >= 0.f && y0f <= 511.f) ? 1.f : 0.f;
                    const float vy1 = (y1f >= 0.f && y1f <= 511.f) ? 1.f : 0.f;
                    const float vx0 = (x0f >= 0.f && x0f <= 511.f) ? 1.f : 0.f;
                    const float vx1 = (x1f >= 0.f && x1f <= 511.f) ? 1.f : 0.f;
                    const int yi0 = iclamp(iy0, 0, 511);
                    const int yi1 = iclamp(iy0 + 1, 0, 511);
                    const int xi0 = iclamp(ix0, 0, 511);
                    const int xi1 = iclamp(ix0 + 1, 0, 511);
                    v00 = xb[(yi0 << 9) + xi0] * (vy0 * vx0);
                    v01 = xb[(yi0 << 9) + xi1] * (vy0 * vx1);
                    v10 = xb[(yi1 << 9) + xi0] * (vy1 * vx0);
                    v11 = xb[(yi1 << 9) + xi1] * (vy1 * vx1);
                }

                const float top = fmaf(lx, v01 - v00, v00);
                const float bot = fmaf(lx, v11 - v10, v10);
                const float val = fmaf(ly, bot - top, top);
                const float s   = val * m2[p];

                if (p == 0) {
                    a00 = fmaf(w0[kk], s, a00);
                    a10 = fmaf(w1[kk], s, a10);
                    a20 = fmaf(w2[kk], s, a20);
                } else {
                    a01 = fmaf(w0[kk], s, a01);
                    a11 = fmaf(w1[kk], s, a11);
                    a21 = fmaf(w2[kk], s, a21);
                }
            }
        }
    }

    const int ob = b * (COUT_ * PLANE_) + pix;
    f2 o0 = {a00 + b0, a01 + b0};
    f2 o1 = {a10 + b1, a11 + b1};
    f2 o2 = {a20 + b2, a21 + b2};
    *(f2*)(out + ob)              = o0;
    *(f2*)(out + ob + PLANE_)     = o1;
    *(f2*)(out + ob + 2 * PLANE_) = o2;
}

// ---------- fallback (no workspace): R10 direct-gather kernel ----------
__global__ __launch_bounds__(256) void dcn_fwd_direct(
    const float* __restrict__ x, const float* __restrict__ offset,
    const float* __restrict__ mask, const float* __restrict__ weight,
    const float* __restrict__ bias, float* __restrict__ out)
{
    const int bid = blockIdx.x;
    const int ho  = bid % HO_;
    const int b   = bid / HO_;
    const int j   = threadIdx.x;
    int wo0 = 2 * j;
    if (wo0 > WO_ - 2) wo0 = WO_ - 2;

    const int pix = ho * WO_ + wo0;
    const float* xb   = x + (b << 18);
    const float* offb = offset + b * (2 * KK_ * PLANE_) + pix;
    const float* mb   = mask   + b * (KK_ * PLANE_)    + pix;

    float w0[KK_], w1[KK_], w2[KK_];
    #pragma unroll
    for (int k = 0; k < KK_; ++k) {
        w0[k] = weight[0 * KK_ + k];
        w1[k] = weight[1 * KK_ + k];
        w2[k] = weight[2 * KK_ + k];
    }
    const float b0 = bias[0], b1 = bias[1], b2 = bias[2];
    const float fho = (float)ho, fwo = (float)wo0;

    float a00 = 0.f, a01 = 0.f, a10 = 0.f, a11 = 0.f, a20 = 0.f, a21 = 0.f;

    #pragma unroll
    for (int kh = 0; kh < 3; ++kh) {
        #pragma unroll
        for (int kw = 0; kw < 3; ++kw) {
            const int kk = kh * 3 + kw;
            const f2 dy2 = *(const f2*)(offb + (2 * kk)     * PLANE_);
            const f2 dx2 = *(const f2*)(offb + (2 * kk + 1) * PLANE_);
            const f2 m2  = *(const f2*)(mb   +  kk          * PLANE_);
            #pragma unroll
            for (int p = 0; p < 2; ++p) {
                const float py = (fho + (float)kh) + dy2[p];
                const float px = (fwo + (float)(kw + p)) + dx2[p];
                const float y0f = floorf(py), x0f = floorf(px);
                const float ly = py - y0f, lx = px - x0f;
                const float y1f = y0f + 1.0f, x1f = x0f + 1.0f;
                const float vy0 = (y0f >= 0.f && y0f <= 511.f) ? 1.f : 0.f;
                const float vy1 = (y1f >= 0.f && y1f <= 511.f) ? 1.f : 0.f;
                const float vx0 = (x0f >= 0.f && x0f <= 511.f) ? 1.f : 0.f;
                const float vx1 = (x1f >= 0.f && x1f <= 511.f) ? 1.f : 0.f;
                const int yi0 = iclamp((int)y0f, 0, 511);
                const int yi1 = iclamp((int)y1f, 0, 511);
                const int xi0 = iclamp((int)x0f, 0, 511);
                const int xi1 = iclamp((int)x1f, 0, 511);
                const float v00 = xb[(yi0 << 9) + xi0] * (vy0 * vx0);
                const float v01 = xb[(yi0 << 9) + xi1] * (vy0 * vx1);
                const float v10 = xb[(yi1 << 9) + xi0] * (vy1 * vx0);
                const float v11 = xb[(yi1 << 9) + xi1] * (vy1 * vx1);
                const float top = fmaf(lx, v01 - v00, v00);
                const float bot = fmaf(lx, v11 - v10, v10);
                const float val = fmaf(ly, bot - top, top);
                const float s   = val * m2[p];
                if (p == 0) { a00 = fmaf(w0[kk], s, a00); a10 = fmaf(w1[kk], s, a10); a20 = fmaf(w2[kk], s, a20); }
                else        { a01 = fmaf(w0[kk], s, a01); a11 = fmaf(w1[kk], s, a11); a21 = fmaf(w2[kk], s, a21); }
            }
        }
    }
    const int ob = b * (COUT_ * PLANE_) + pix;
    f2 o0 = {a00 + b0, a01 + b0};
    f2 o1 = {a10 + b1, a11 + b1};
    f2 o2 = {a20 + b2, a21 + b2};
    *(f2*)(out + ob)              = o0;
    *(f2*)(out + ob + PLANE_)     = o1;
    *(f2*)(out + ob + 2 * PLANE_) = o2;
}

extern "C" void kernel_launch(void* const* d_in, const int* in_sizes, int n_in,
                              void* d_out, int out_size, void* d_ws, size_t ws_size,
                              hipStream_t stream) {
    const float* x      = (const float*)d_in[0];
    const float* offset = (const float*)d_in[1];
    const float* mask   = (const float*)d_in[2];
    const float* weight = (const float*)d_in[3];
    const float* bias   = (const float*)d_in[4];
    float* out = (float*)d_out;

    const size_t t_bytes = (size_t)B_ * 512 * 512 * sizeof(float4);   // 32 MiB

    if (ws_size >= t_bytes) {
        float4* T = (float4*)d_ws;
        pack_quads<<<(B_ * 512 * 512) / 256, 256, 0, stream>>>(x, T);
        dcn_fwd_quad<<<B_ * HO_, 256, 0, stream>>>(x, T, offset, mask, weight, bias, out);
    } else {
        dcn_fwd_direct<<<B_ * HO_, 256, 0, stream>>>(x, offset, mask, weight, bias, out);
    }
}